// Round 1
// baseline (107.614 us; speedup 1.0000x reference)
//
#include <hip/hip_runtime.h>

#define ALPHA 0.2f

constexpr int Bc = 32, Nc = 1024, Dc = 64, Hc = 4, Ec = 16;

// ---------------------------------------------------------------------------
// Kernel 1: h[b][h][n][e] = sum_d input[b][n][d] * W[h][d][e]
//           s_dst[b][h][n] = sum_e h * a[e];  s_src = sum_e h * a[E+e]
// One thread per (b,h,n) row. Block = 256 threads covers 256 consecutive n
// for a fixed (b,h) -> whole block shares one W head slice (4 KB in LDS).
// ---------------------------------------------------------------------------
__global__ __launch_bounds__(256) void gat_proj(const float* __restrict__ input,
                                                const float* __restrict__ W,
                                                const float* __restrict__ a,
                                                float* __restrict__ h_out,
                                                float* __restrict__ s_src,
                                                float* __restrict__ s_dst) {
    __shared__ float W_lds[Dc * Ec];   // 4 KB: this block's head slice
    __shared__ float a_lds[2 * Ec];

    const int tid = threadIdx.x;
    const int gid = blockIdx.x * 256 + tid;   // ((b*H + h)*N + n)
    const int n   = gid & (Nc - 1);
    const int bh  = gid >> 10;
    const int hh  = bh & (Hc - 1);
    const int b   = bh >> 2;

    // stage W[hh] (1024 floats) and a (32 floats)
    ((float4*)W_lds)[tid] = ((const float4*)(W + hh * Dc * Ec))[tid];
    if (tid < 2 * Ec) a_lds[tid] = a[tid];
    __syncthreads();

    const float4* in_row = (const float4*)(input + ((size_t)b * Nc + n) * Dc);

    float acc[Ec];
#pragma unroll
    for (int e = 0; e < Ec; ++e) acc[e] = 0.f;

#pragma unroll
    for (int d4 = 0; d4 < Dc / 4; ++d4) {
        float4 x = in_row[d4];
        float xs[4] = {x.x, x.y, x.z, x.w};
#pragma unroll
        for (int k = 0; k < 4; ++k) {
            const float xv = xs[k];
            const float* wrow = &W_lds[(d4 * 4 + k) * Ec];
#pragma unroll
            for (int e = 0; e < Ec; ++e) acc[e] = fmaf(xv, wrow[e], acc[e]);
        }
    }

    float* hrow = h_out + (size_t)gid * Ec;
#pragma unroll
    for (int e4 = 0; e4 < Ec / 4; ++e4)
        ((float4*)hrow)[e4] =
            make_float4(acc[e4 * 4], acc[e4 * 4 + 1], acc[e4 * 4 + 2], acc[e4 * 4 + 3]);

    float sd = 0.f, ss = 0.f;
#pragma unroll
    for (int e = 0; e < Ec; ++e) {
        sd = fmaf(acc[e], a_lds[e], sd);        // a_dst = a[:E]
        ss = fmaf(acc[e], a_lds[Ec + e], ss);   // a_src = a[E:]
    }
    s_dst[gid] = sd;
    s_src[gid] = ss;
}

// ---------------------------------------------------------------------------
// Kernel 2: per (b,h): out[i,:] = sum_j softmax_j(lrelu(s_src[i]+s_dst[j])) h[j,:]
// Grid (B*H, 4 row-tiles), block 256, one row per thread.
// h[b,h] (64 KB) + s_dst (4 KB) staged in LDS -> 2 WG/CU, 512 WG total.
// All lanes read the same h_lds[j][*] per step -> broadcast, conflict-free.
// ---------------------------------------------------------------------------
__global__ __launch_bounds__(256) void gat_attn(const float* __restrict__ h,
                                                const float* __restrict__ s_src,
                                                const float* __restrict__ s_dst,
                                                float* __restrict__ out) {
    __shared__ float h_lds[Nc * Ec];   // 64 KB
    __shared__ float sd_lds[Nc];       // 4 KB
    __shared__ float red[4];

    const int bh  = blockIdx.x;        // 0..127
    const int tid = threadIdx.x;

    // stage h[b,h] : 4096 float4s
    const float4* hb4 = (const float4*)(h + (size_t)bh * Nc * Ec);
#pragma unroll
    for (int k = 0; k < (Nc * Ec / 4) / 256; ++k)
        ((float4*)h_lds)[k * 256 + tid] = hb4[k * 256 + tid];
#pragma unroll
    for (int k = 0; k < Nc / 256; ++k)
        sd_lds[k * 256 + tid] = s_dst[bh * Nc + k * 256 + tid];
    __syncthreads();

    // block-wide max of s_dst (monotone lrelu => rowmax_i = lrelu(s_i + maxd))
    float m = -1e30f;
#pragma unroll
    for (int k = 0; k < Nc / 256; ++k) m = fmaxf(m, sd_lds[k * 256 + tid]);
#pragma unroll
    for (int off = 1; off < 64; off <<= 1) m = fmaxf(m, __shfl_xor(m, off, 64));
    if ((tid & 63) == 0) red[tid >> 6] = m;
    __syncthreads();
    const float maxd = fmaxf(fmaxf(red[0], red[1]), fmaxf(red[2], red[3]));

    const int i  = blockIdx.y * 256 + tid;
    const float si = s_src[bh * Nc + i];
    const float t  = si + maxd;
    const float rowmax = t > 0.f ? t : ALPHA * t;

    float acc[Ec];
#pragma unroll
    for (int e = 0; e < Ec; ++e) acc[e] = 0.f;
    float den = 0.f;

#pragma unroll 4
    for (int j = 0; j < Nc; ++j) {
        float x = si + sd_lds[j];
        x = x > 0.f ? x : ALPHA * x;
        const float w = __expf(x - rowmax);
        den += w;
        const float4* hj = (const float4*)&h_lds[j * Ec];
        float4 h0 = hj[0], h1 = hj[1], h2 = hj[2], h3 = hj[3];
        acc[0]  = fmaf(w, h0.x, acc[0]);  acc[1]  = fmaf(w, h0.y, acc[1]);
        acc[2]  = fmaf(w, h0.z, acc[2]);  acc[3]  = fmaf(w, h0.w, acc[3]);
        acc[4]  = fmaf(w, h1.x, acc[4]);  acc[5]  = fmaf(w, h1.y, acc[5]);
        acc[6]  = fmaf(w, h1.z, acc[6]);  acc[7]  = fmaf(w, h1.w, acc[7]);
        acc[8]  = fmaf(w, h2.x, acc[8]);  acc[9]  = fmaf(w, h2.y, acc[9]);
        acc[10] = fmaf(w, h2.z, acc[10]); acc[11] = fmaf(w, h2.w, acc[11]);
        acc[12] = fmaf(w, h3.x, acc[12]); acc[13] = fmaf(w, h3.y, acc[13]);
        acc[14] = fmaf(w, h3.z, acc[14]); acc[15] = fmaf(w, h3.w, acc[15]);
    }

    const float inv = 1.f / den;
    // raw reshape (B,H,N,E)->(B,N,H*E) preserves flat order: write natural layout
    float* orow = out + ((size_t)bh * Nc + i) * Ec;
#pragma unroll
    for (int e4 = 0; e4 < Ec / 4; ++e4)
        ((float4*)orow)[e4] = make_float4(acc[e4 * 4] * inv, acc[e4 * 4 + 1] * inv,
                                          acc[e4 * 4 + 2] * inv, acc[e4 * 4 + 3] * inv);
}

extern "C" void kernel_launch(void* const* d_in, const int* in_sizes, int n_in,
                              void* d_out, int out_size, void* d_ws, size_t ws_size,
                              hipStream_t stream) {
    const float* input = (const float*)d_in[0];
    // d_in[1] = adj : UNUSED by the reference
    const float* W = (const float*)d_in[2];
    const float* a = (const float*)d_in[3];
    float* out = (float*)d_out;

    float* h_ws   = (float*)d_ws;                       // B*H*N*E = 2M floats
    float* s_src  = h_ws + (size_t)Bc * Hc * Nc * Ec;   // B*H*N
    float* s_dst  = s_src + (size_t)Bc * Hc * Nc;       // B*H*N

    gat_proj<<<dim3(Bc * Hc * Nc / 256), dim3(256), 0, stream>>>(input, W, a, h_ws,
                                                                 s_src, s_dst);
    gat_attn<<<dim3(Bc * Hc, Nc / 256), dim3(256), 0, stream>>>(h_ws, s_src, s_dst, out);
}

// Round 3
// 49.623 us; speedup vs baseline: 2.1686x; 2.1686x over previous
//
#include <hip/hip_runtime.h>

#define ALPHA 0.2f

constexpr int Bc = 32, Nc = 1024, Dc = 64, Hc = 4, Ec = 16;
constexpr int PITCH = 19;   // 18 scan columns + 1 pad (gcd(19,32)=1 -> spread banks)

// ---------------------------------------------------------------------------
// Kernel 1 (unchanged): h = input @ W per head; s_src/s_dst = h @ a halves.
// ---------------------------------------------------------------------------
__global__ __launch_bounds__(256) void gat_proj(const float* __restrict__ input,
                                                const float* __restrict__ W,
                                                const float* __restrict__ a,
                                                float* __restrict__ h_out,
                                                float* __restrict__ s_src,
                                                float* __restrict__ s_dst) {
    __shared__ float W_lds[Dc * Ec];
    __shared__ float a_lds[2 * Ec];

    const int tid = threadIdx.x;
    const int gid = blockIdx.x * 256 + tid;   // ((b*H + h)*N + n)
    const int n   = gid & (Nc - 1);
    const int bh  = gid >> 10;
    const int hh  = bh & (Hc - 1);
    const int b   = bh >> 2;

    ((float4*)W_lds)[tid] = ((const float4*)(W + hh * Dc * Ec))[tid];
    if (tid < 2 * Ec) a_lds[tid] = a[tid];
    __syncthreads();

    const float4* in_row = (const float4*)(input + ((size_t)b * Nc + n) * Dc);

    float acc[Ec];
#pragma unroll
    for (int e = 0; e < Ec; ++e) acc[e] = 0.f;

#pragma unroll
    for (int d4 = 0; d4 < Dc / 4; ++d4) {
        float4 x = in_row[d4];
        float xs[4] = {x.x, x.y, x.z, x.w};
#pragma unroll
        for (int k = 0; k < 4; ++k) {
            const float xv = xs[k];
            const float* wrow = &W_lds[(d4 * 4 + k) * Ec];
#pragma unroll
            for (int e = 0; e < Ec; ++e) acc[e] = fmaf(xv, wrow[e], acc[e]);
        }
    }

    float* hrow = h_out + (size_t)gid * Ec;
#pragma unroll
    for (int e4 = 0; e4 < Ec / 4; ++e4)
        ((float4*)hrow)[e4] =
            make_float4(acc[e4 * 4], acc[e4 * 4 + 1], acc[e4 * 4 + 2], acc[e4 * 4 + 3]);

    float sd = 0.f, ss = 0.f;
#pragma unroll
    for (int e = 0; e < Ec; ++e) {
        sd = fmaf(acc[e], a_lds[e], sd);
        ss = fmaf(acc[e], a_lds[Ec + e], ss);
    }
    s_dst[gid] = sd;
    s_src[gid] = ss;
}

// ---------------------------------------------------------------------------
// Kernel 2: separable-softmax prefix-sum algorithm.
//   P_ij = u_j                     if s_i + s_dj > 0
//        = C_i * v_j               otherwise
//   u_j = exp(s_dj - maxd), v_j = exp(0.2(s_dj - maxd)),
//   C_i = exp(-0.8(s_i + maxd))  (C_i = 1 when s_i + maxd < 0, then k_i = 0).
// Sort s_dst desc; out_i = (Pref_u[k_i] + C_i*(Tot_v - Pref_v[k_i])) / den.
// Block = (bh, half of E), 1024 threads, one element/row per thread.
// ---------------------------------------------------------------------------
__device__ inline unsigned int f2ord(float f) {
    unsigned int u = __float_as_uint(f);
    return (u & 0x80000000u) ? ~u : (u | 0x80000000u);   // monotone-ascending map
}
__device__ inline float ord2f(unsigned int s) {
    unsigned int u = (s & 0x80000000u) ? (s & 0x7fffffffu) : ~s;
    return __uint_as_float(u);
}

__global__ __launch_bounds__(1024) void gat_attn2(const float* __restrict__ h,
                                                  const float* __restrict__ s_src,
                                                  const float* __restrict__ s_dst,
                                                  float* __restrict__ out) {
    __shared__ unsigned long long sortbuf[Nc];       // 8 KB
    __shared__ float key[Nc];                        // 4 KB  (sorted s_dst, desc)
    __shared__ int   idx[Nc];                        // 4 KB  (permutation)
    __shared__ float scanbuf[(Nc + 1) * PITCH];      // 77.9 KB
    __shared__ float totH[18];

    const int bh   = blockIdx.x;     // 0..127
    const int half = blockIdx.y;     // 0..1 (which 8 of the 16 e's)
    const int tid  = threadIdx.x;

    // ---- 1. pack (orderable-key | index) and bitonic-sort descending ----
    sortbuf[tid] = ((unsigned long long)f2ord(s_dst[bh * Nc + tid]) << 32) | (unsigned)tid;
    __syncthreads();

    for (int ks = 2; ks <= Nc; ks <<= 1) {
        for (int js = ks >> 1; js > 0; js >>= 1) {
            const int l = tid ^ js;
            if (l > tid) {
                unsigned long long a = sortbuf[tid], b = sortbuf[l];
                const bool desc = ((tid & ks) == 0);
                if (desc ? (a < b) : (a > b)) { sortbuf[tid] = b; sortbuf[l] = a; }
            }
            __syncthreads();
        }
    }

    {
        unsigned long long p = sortbuf[tid];
        key[tid] = ord2f((unsigned int)(p >> 32));
        idx[tid] = (int)(unsigned int)(p & 0xffffffffu);
    }
    __syncthreads();

    const float maxd = key[0];

    // ---- 2. build scan elements: [u*h(8) | v*h(8) | u | v] ----
    {
        const float x  = key[tid] - maxd;            // <= 0
        const float uu = __expf(x);
        const float vv = __expf(0.2f * x);
        const float* hrow = h + ((size_t)bh * Nc + idx[tid]) * Ec + half * 8;
        const float4 ha = *(const float4*)hrow;
        const float4 hb = *(const float4*)(hrow + 4);
        float* row = &scanbuf[tid * PITCH];
        row[0] = uu * ha.x; row[1] = uu * ha.y; row[2] = uu * ha.z; row[3] = uu * ha.w;
        row[4] = uu * hb.x; row[5] = uu * hb.y; row[6] = uu * hb.z; row[7] = uu * hb.w;
        row[8]  = vv * ha.x; row[9]  = vv * ha.y; row[10] = vv * ha.z; row[11] = vv * ha.w;
        row[12] = vv * hb.x; row[13] = vv * hb.y; row[14] = vv * hb.z; row[15] = vv * hb.w;
        row[16] = uu; row[17] = vv;
    }
    __syncthreads();

    // ---- 3. Blelloch exclusive scan over 1024 rows x 18 columns ----
    for (int d = 1; d < Nc; d <<= 1) {
        if (tid < (Nc >> 1) / d) {
            const int i = (tid + 1) * (d << 1) - 1;
            float* a = &scanbuf[i * PITCH];
            float* b = &scanbuf[(i - d) * PITCH];
#pragma unroll
            for (int c = 0; c < 18; ++c) a[c] += b[c];
        }
        __syncthreads();
    }
    if (tid < 18) {
        totH[tid] = scanbuf[(Nc - 1) * PITCH + tid];
        scanbuf[(Nc - 1) * PITCH + tid] = 0.f;
    }
    __syncthreads();
    for (int d = Nc >> 1; d >= 1; d >>= 1) {
        if (tid < (Nc >> 1) / d) {
            const int i = (tid + 1) * (d << 1) - 1;
            float* a = &scanbuf[i * PITCH];
            float* b = &scanbuf[(i - d) * PITCH];
#pragma unroll
            for (int c = 0; c < 18; ++c) { float t = b[c]; b[c] = a[c]; a[c] += t; }
        }
        __syncthreads();
    }
    // row Nc = totals, so prefix lookup is uniform for k = 0..1024
    if (tid < 18) scanbuf[Nc * PITCH + tid] = totH[tid];
    __syncthreads();

    // ---- 4. per-row: binary search cut point, combine prefixes ----
    {
        const int i  = tid;
        const float si = s_src[bh * Nc + i];
        const float c1 = si + maxd;
        const float C  = (c1 >= 0.f) ? __expf(-0.8f * c1) : 1.0f;

        // k = #{t : key[t] > -si}, key descending; exactly 10 uniform iterations
        const float thr = -si;
        int lo = 0, hi = Nc;
        while (lo < hi) {
            const int mid = (lo + hi) >> 1;
            if (key[mid] > thr) lo = mid + 1; else hi = mid;
        }
        const int k = lo;

        const float* pk = &scanbuf[(size_t)k * PITCH];
        const float den = pk[16] + C * (totH[17] - pk[17]);
        const float inv = 1.0f / den;

        float o[8];
#pragma unroll
        for (int c = 0; c < 8; ++c)
            o[c] = (pk[c] + C * (totH[8 + c] - pk[8 + c])) * inv;

        float* orow = out + ((size_t)bh * Nc + i) * Ec + half * 8;
        *(float4*)orow       = make_float4(o[0], o[1], o[2], o[3]);
        *(float4*)(orow + 4) = make_float4(o[4], o[5], o[6], o[7]);
    }
}

extern "C" void kernel_launch(void* const* d_in, const int* in_sizes, int n_in,
                              void* d_out, int out_size, void* d_ws, size_t ws_size,
                              hipStream_t stream) {
    const float* input = (const float*)d_in[0];
    // d_in[1] = adj : UNUSED by the reference
    const float* W = (const float*)d_in[2];
    const float* a = (const float*)d_in[3];
    float* out = (float*)d_out;

    float* h_ws  = (float*)d_ws;                       // B*H*N*E = 2M floats
    float* s_src = h_ws + (size_t)Bc * Hc * Nc * Ec;   // B*H*N
    float* s_dst = s_src + (size_t)Bc * Hc * Nc;       // B*H*N

    gat_proj<<<dim3(Bc * Hc * Nc / 256), dim3(256), 0, stream>>>(input, W, a, h_ws,
                                                                 s_src, s_dst);
    gat_attn2<<<dim3(Bc * Hc, 2), dim3(1024), 0, stream>>>(h_ws, s_src, s_dst, out);
}

// Round 4
// 35.640 us; speedup vs baseline: 3.0194x; 1.3923x over previous
//
#include <hip/hip_runtime.h>

#define ALPHA 0.2f

constexpr int Bc = 32, Nc = 1024, Dc = 64, Hc = 4, Ec = 16;
constexpr int PITCH = 19;   // 18 scan columns + 1 pad (odd -> at worst 2-way bank alias)

// ---------------------------------------------------------------------------
// Kernel 1 (unchanged): h = input @ W per head; s_src/s_dst = h @ a halves.
// ---------------------------------------------------------------------------
__global__ __launch_bounds__(256) void gat_proj(const float* __restrict__ input,
                                                const float* __restrict__ W,
                                                const float* __restrict__ a,
                                                float* __restrict__ h_out,
                                                float* __restrict__ s_src,
                                                float* __restrict__ s_dst) {
    __shared__ float W_lds[Dc * Ec];
    __shared__ float a_lds[2 * Ec];

    const int tid = threadIdx.x;
    const int gid = blockIdx.x * 256 + tid;   // ((b*H + h)*N + n)
    const int n   = gid & (Nc - 1);
    const int bh  = gid >> 10;
    const int hh  = bh & (Hc - 1);
    const int b   = bh >> 2;

    ((float4*)W_lds)[tid] = ((const float4*)(W + hh * Dc * Ec))[tid];
    if (tid < 2 * Ec) a_lds[tid] = a[tid];
    __syncthreads();

    const float4* in_row = (const float4*)(input + ((size_t)b * Nc + n) * Dc);

    float acc[Ec];
#pragma unroll
    for (int e = 0; e < Ec; ++e) acc[e] = 0.f;

#pragma unroll
    for (int d4 = 0; d4 < Dc / 4; ++d4) {
        float4 x = in_row[d4];
        float xs[4] = {x.x, x.y, x.z, x.w};
#pragma unroll
        for (int k = 0; k < 4; ++k) {
            const float xv = xs[k];
            const float* wrow = &W_lds[(d4 * 4 + k) * Ec];
#pragma unroll
            for (int e = 0; e < Ec; ++e) acc[e] = fmaf(xv, wrow[e], acc[e]);
        }
    }

    float* hrow = h_out + (size_t)gid * Ec;
#pragma unroll
    for (int e4 = 0; e4 < Ec / 4; ++e4)
        ((float4*)hrow)[e4] =
            make_float4(acc[e4 * 4], acc[e4 * 4 + 1], acc[e4 * 4 + 2], acc[e4 * 4 + 3]);

    float sd = 0.f, ss = 0.f;
#pragma unroll
    for (int e = 0; e < Ec; ++e) {
        sd = fmaf(acc[e], a_lds[e], sd);
        ss = fmaf(acc[e], a_lds[Ec + e], ss);
    }
    s_dst[gid] = sd;
    s_src[gid] = ss;
}

// ---------------------------------------------------------------------------
// Kernel 2: separable-softmax prefix-sum, barrier-minimal schedule.
//   Sort: register bitonic; intra-wave passes via shfl_xor, only js>=64 via LDS.
//   Scan: wave-level shfl_up inclusive scan of 18 columns + wave-offset fixup.
// ---------------------------------------------------------------------------
__device__ inline unsigned int f2ord(float f) {
    unsigned int u = __float_as_uint(f);
    return (u & 0x80000000u) ? ~u : (u | 0x80000000u);   // monotone-ascending map
}
__device__ inline float ord2f(unsigned int s) {
    unsigned int u = (s & 0x80000000u) ? (s & 0x7fffffffu) : ~s;
    return __uint_as_float(u);
}
__device__ inline unsigned long long shflxor64(unsigned long long v, int m) {
    int lo = __shfl_xor((int)(unsigned int)(v & 0xffffffffull), m, 64);
    int hi = __shfl_xor((int)(unsigned int)(v >> 32), m, 64);
    return ((unsigned long long)(unsigned int)hi << 32) | (unsigned int)lo;
}
__device__ inline unsigned long long cmpex(unsigned long long v, unsigned long long p,
                                           bool keepmax) {
    return keepmax ? (v > p ? v : p) : (v < p ? v : p);
}

__global__ __launch_bounds__(1024) void gat_attn3(const float* __restrict__ h,
                                                  const float* __restrict__ s_src,
                                                  const float* __restrict__ s_dst,
                                                  float* __restrict__ out) {
    // scanbuf doubles as the u64 sort-exchange buffer (sort completes first)
    __shared__ alignas(16) float scanbuf[(Nc + 1) * PITCH];   // 77.9 KB
    __shared__ float key[Nc];                                  // 4 KB
    __shared__ float segtot[16][20];                           // wave offsets, padded
    __shared__ float tot[18];

    const int bh   = blockIdx.x;      // 0..127
    const int half = blockIdx.y;      // 0..1
    const int tid  = threadIdx.x;
    const int lane = tid & 63;
    const int wave = tid >> 6;

    // ---- 1. register bitonic sort (descending), key = s_dst, payload = idx --
    unsigned long long val =
        ((unsigned long long)f2ord(s_dst[bh * Nc + tid]) << 32) | (unsigned int)tid;

    // stages ks=2..64: fully intra-wave
#pragma unroll
    for (int ks = 2; ks <= 64; ks <<= 1) {
#pragma unroll
        for (int js = ks >> 1; js > 0; js >>= 1) {
            unsigned long long p = shflxor64(val, js);
            val = cmpex(val, p, ((tid & js) == 0) == ((tid & ks) == 0));
        }
    }
    // stages ks=128..1024: js>=64 via LDS, js<=32 intra-wave
    unsigned long long* sbuf = (unsigned long long*)scanbuf;
#pragma unroll
    for (int ks = 128; ks <= Nc; ks <<= 1) {
        for (int js = ks >> 1; js >= 64; js >>= 1) {
            __syncthreads();
            sbuf[tid] = val;
            __syncthreads();
            unsigned long long p = sbuf[tid ^ js];
            val = cmpex(val, p, ((tid & js) == 0) == ((tid & ks) == 0));
        }
#pragma unroll
        for (int js = 32; js > 0; js >>= 1) {
            unsigned long long p = shflxor64(val, js);
            val = cmpex(val, p, ((tid & js) == 0) == ((tid & ks) == 0));
        }
    }

    const float keyr  = ord2f((unsigned int)(val >> 32));
    const int   myidx = (int)(unsigned int)(val & 0xffffffffu);
    __syncthreads();              // sort LDS reads done before scanbuf reuse
    key[tid] = keyr;
    __syncthreads();
    const float maxd = key[0];

    // ---- 2. build 18 scan values in registers ----
    const float x  = keyr - maxd;                 // <= 0
    const float uu = __expf(x);
    const float vv = __expf(0.2f * x);
    const float* hrow = h + ((size_t)bh * Nc + myidx) * Ec + half * 8;
    const float4 ha = *(const float4*)hrow;
    const float4 hb = *(const float4*)(hrow + 4);

    float vals[18] = {uu * ha.x, uu * ha.y, uu * ha.z, uu * ha.w,
                      uu * hb.x, uu * hb.y, uu * hb.z, uu * hb.w,
                      vv * ha.x, vv * ha.y, vv * ha.z, vv * ha.w,
                      vv * hb.x, vv * hb.y, vv * hb.z, vv * hb.w,
                      uu, vv};

    // ---- 3. hierarchical inclusive scan: wave shfl scan + wave offsets ----
#pragma unroll
    for (int off = 1; off < 64; off <<= 1) {
#pragma unroll
        for (int c = 0; c < 18; ++c) {
            float t = __shfl_up(vals[c], off, 64);
            if (lane >= off) vals[c] += t;
        }
    }
    if (lane == 63) {
#pragma unroll
        for (int c = 0; c < 18; ++c) segtot[wave][c] = vals[c];
    }
    __syncthreads();
    if (tid < 18) {      // serial exclusive scan over the 16 wave totals
        float ex = 0.f;
#pragma unroll
        for (int w = 0; w < 16; ++w) {
            float t = segtot[w][tid];
            segtot[w][tid] = ex;
            ex += t;
        }
        tot[tid] = ex;
    }
    __syncthreads();
    {
        float* row = &scanbuf[(size_t)(tid + 1) * PITCH];
#pragma unroll
        for (int c = 0; c < 18; ++c) row[c] = vals[c] + segtot[wave][c];
        if (tid == 0) {
#pragma unroll
            for (int c = 0; c < 18; ++c) scanbuf[c] = 0.f;
        }
    }
    __syncthreads();

    // ---- 4. per-row: binary search cut, combine prefixes ----
    {
        const float si = s_src[bh * Nc + tid];
        const float c1 = si + maxd;
        const float C  = (c1 >= 0.f) ? __expf(-0.8f * c1) : 1.0f;

        const float thr = -si;       // k = #{t : key[t] > -si}, key descending
        int lo = 0, hi = Nc;
        while (lo < hi) {
            const int mid = (lo + hi) >> 1;
            if (key[mid] > thr) lo = mid + 1; else hi = mid;
        }

        const float* pk = &scanbuf[(size_t)lo * PITCH];   // inclusive prefix of first lo
        const float den = pk[16] + C * (tot[17] - pk[17]);
        const float inv = 1.0f / den;

        float o[8];
#pragma unroll
        for (int c = 0; c < 8; ++c)
            o[c] = (pk[c] + C * (tot[8 + c] - pk[8 + c])) * inv;

        float* orow = out + ((size_t)bh * Nc + tid) * Ec + half * 8;
        *(float4*)orow       = make_float4(o[0], o[1], o[2], o[3]);
        *(float4*)(orow + 4) = make_float4(o[4], o[5], o[6], o[7]);
    }
}

extern "C" void kernel_launch(void* const* d_in, const int* in_sizes, int n_in,
                              void* d_out, int out_size, void* d_ws, size_t ws_size,
                              hipStream_t stream) {
    const float* input = (const float*)d_in[0];
    // d_in[1] = adj : UNUSED by the reference
    const float* W = (const float*)d_in[2];
    const float* a = (const float*)d_in[3];
    float* out = (float*)d_out;

    float* h_ws  = (float*)d_ws;                       // B*H*N*E = 2M floats
    float* s_src = h_ws + (size_t)Bc * Hc * Nc * Ec;   // B*H*N
    float* s_dst = s_src + (size_t)Bc * Hc * Nc;       // B*H*N

    gat_proj<<<dim3(Bc * Hc * Nc / 256), dim3(256), 0, stream>>>(input, W, a, h_ws,
                                                                 s_src, s_dst);
    gat_attn3<<<dim3(Bc * Hc, 2), dim3(1024), 0, stream>>>(h_ws, s_src, s_dst, out);
}

// Round 5
// 28.453 us; speedup vs baseline: 3.7821x; 1.2526x over previous
//
#include <hip/hip_runtime.h>

typedef _Float16 f16;
typedef f16 f16x8 __attribute__((ext_vector_type(8)));
typedef float f32x4 __attribute__((ext_vector_type(4)));

constexpr int Bc = 32, Nc = 1024, Dc = 64, Hc = 4, Ec = 16;
constexpr int HP = 1032;   // h_t pitch (f16): 1024+8 -> B-frag reads 2-way max bank alias

// ---------------------------------------------------------------------------
// Kernel 1: h = input @ W per head. Stores h TRANSPOSED as f16 [bh][e][j]
// (MFMA B-operand layout) plus fp32 score vectors s_src/s_dst.
// ---------------------------------------------------------------------------
__global__ __launch_bounds__(256) void gat_proj(const float* __restrict__ input,
                                                const float* __restrict__ W,
                                                const float* __restrict__ a,
                                                f16* __restrict__ h16t,
                                                float* __restrict__ s_src,
                                                float* __restrict__ s_dst) {
    __shared__ float W_lds[Dc * Ec];
    __shared__ float a_lds[2 * Ec];

    const int tid = threadIdx.x;
    const int gid = blockIdx.x * 256 + tid;   // ((b*H + h)*N + n)
    const int n   = gid & (Nc - 1);
    const int bh  = gid >> 10;
    const int hh  = bh & (Hc - 1);
    const int b   = bh >> 2;

    ((float4*)W_lds)[tid] = ((const float4*)(W + hh * Dc * Ec))[tid];
    if (tid < 2 * Ec) a_lds[tid] = a[tid];
    __syncthreads();

    const float4* in_row = (const float4*)(input + ((size_t)b * Nc + n) * Dc);

    float acc[Ec];
#pragma unroll
    for (int e = 0; e < Ec; ++e) acc[e] = 0.f;

#pragma unroll
    for (int d4 = 0; d4 < Dc / 4; ++d4) {
        float4 x = in_row[d4];
        float xs[4] = {x.x, x.y, x.z, x.w};
#pragma unroll
        for (int k = 0; k < 4; ++k) {
            const float xv = xs[k];
            const float* wrow = &W_lds[(d4 * 4 + k) * Ec];
#pragma unroll
            for (int e = 0; e < Ec; ++e) acc[e] = fmaf(xv, wrow[e], acc[e]);
        }
    }

    // transposed f16 store: h16t[bh][e][n]  (lanes n-consecutive -> coalesced)
    f16* hb = h16t + (size_t)bh * Ec * HP + n;
#pragma unroll
    for (int e = 0; e < Ec; ++e) hb[e * HP] = (f16)acc[e];

    float sd = 0.f, ss = 0.f;
#pragma unroll
    for (int e = 0; e < Ec; ++e) {
        sd = fmaf(acc[e], a_lds[e], sd);        // a_dst = a[:E]
        ss = fmaf(acc[e], a_lds[Ec + e], ss);   // a_src = a[E:]
    }
    s_dst[gid] = sd;
    s_src[gid] = ss;
}

// ---------------------------------------------------------------------------
// Kernel 2: per bh: maxd = max_j s_dst; u = exp(sd-maxd); v = exp(0.2(sd-maxd))
// ---------------------------------------------------------------------------
__global__ __launch_bounds__(256) void gat_prep(const float* __restrict__ s_dst,
                                                f16* __restrict__ u16,
                                                f16* __restrict__ v16,
                                                float* __restrict__ maxd_ws) {
    __shared__ float red[4];
    const int bh = blockIdx.x, tid = threadIdx.x;

    float sd[4];
    float m = -1e30f;
#pragma unroll
    for (int k = 0; k < 4; ++k) {
        sd[k] = s_dst[bh * Nc + k * 256 + tid];
        m = fmaxf(m, sd[k]);
    }
#pragma unroll
    for (int off = 1; off < 64; off <<= 1) m = fmaxf(m, __shfl_xor(m, off, 64));
    if ((tid & 63) == 0) red[tid >> 6] = m;
    __syncthreads();
    m = fmaxf(fmaxf(red[0], red[1]), fmaxf(red[2], red[3]));

#pragma unroll
    for (int k = 0; k < 4; ++k) {
        const float x = sd[k] - m;               // <= 0
        u16[bh * Nc + k * 256 + tid] = (f16)__expf(x);
        v16[bh * Nc + k * 256 + tid] = (f16)__expf(0.2f * x);
    }
    if (tid == 0) maxd_ws[bh] = m;
}

// ---------------------------------------------------------------------------
// Kernel 3: P_ij = max(u_j, C_i*v_j) built in packed f16; out = (P@h)/(P@1)
// via mfma_f32_16x16x32_f16. Block = (bh, i-half): 8 waves x 4 i-tiles x K=1024.
// ---------------------------------------------------------------------------
__global__ __launch_bounds__(512) void gat_attn4(const f16* __restrict__ h16t,
                                                 const f16* __restrict__ u16,
                                                 const f16* __restrict__ v16,
                                                 const float* __restrict__ s_src,
                                                 const float* __restrict__ maxd_ws,
                                                 float* __restrict__ out) {
    __shared__ alignas(16) f16 h_t[Ec * HP];     // 33 KB

    const int bh    = blockIdx.x;      // 0..127
    const int ihalf = blockIdx.y;      // 0..1
    const int tid   = threadIdx.x;
    const int lane  = tid & 63;
    const int wave  = tid >> 6;        // 0..7
    const int row   = lane & 15;       // A-row / B-col / D-col index
    const int quad  = lane >> 4;       // K-quadrant

    // ---- stage h_t (16x1032 f16 = 2064 float4 chunks) ----
    {
        const float4* src = (const float4*)(h16t + (size_t)bh * Ec * HP);
        float4* dst = (float4*)h_t;
        dst[tid]        = src[tid];
        dst[512 + tid]  = src[512 + tid];
        dst[1024 + tid] = src[1024 + tid];
        dst[1536 + tid] = src[1536 + tid];
        if (tid < 16) dst[2048 + tid] = src[2048 + tid];
    }

    // ---- per-row C_i = min(1, exp(-0.8*(s_i + maxd))) ----
    const float maxd  = maxd_ws[bh];
    const int   ibase = ihalf * 512 + wave * 64;
    f16x8 C8[4];
#pragma unroll
    for (int it = 0; it < 4; ++it) {
        const float si = s_src[bh * Nc + ibase + it * 16 + row];
        const float c1 = si + maxd;
        const float Cf = (c1 >= 0.f) ? __expf(-0.8f * c1) : 1.0f;
        const f16 ch = (f16)Cf;
        C8[it] = (f16x8){ch, ch, ch, ch, ch, ch, ch, ch};
    }
    __syncthreads();

    f32x4 accN[4] = {};
    f32x4 accD[4] = {};
    const f16 o1 = (f16)1.f;
    const f16x8 ones = {o1, o1, o1, o1, o1, o1, o1, o1};

    const f16* up = u16 + bh * Nc + quad * 8;
    const f16* vp = v16 + bh * Nc + quad * 8;
    const f16* bp = h_t + row * HP + quad * 8;

#pragma unroll 4
    for (int kt = 0; kt < 32; ++kt) {
        const f16x8 u8 = *(const f16x8*)(up + kt * 32);
        const f16x8 v8 = *(const f16x8*)(vp + kt * 32);
        const f16x8 b8 = *(const f16x8*)(bp + kt * 32);
#pragma unroll
        for (int it = 0; it < 4; ++it) {
            const f16x8 p = __builtin_elementwise_max(u8, C8[it] * v8);
            accN[it] = __builtin_amdgcn_mfma_f32_16x16x32_f16(p, b8,   accN[it], 0, 0, 0);
            accD[it] = __builtin_amdgcn_mfma_f32_16x16x32_f16(p, ones, accD[it], 0, 0, 0);
        }
    }

    // ---- epilogue: D row = quad*4 + r, col = row (m89 C/D layout) ----
#pragma unroll
    for (int it = 0; it < 4; ++it) {
#pragma unroll
        for (int r = 0; r < 4; ++r) {
            const float inv = __builtin_amdgcn_rcpf(accD[it][r]);
            const int i = ibase + it * 16 + quad * 4 + r;
            out[((size_t)(bh * Nc + i)) * Ec + row] = accN[it][r] * inv;
        }
    }
}

extern "C" void kernel_launch(void* const* d_in, const int* in_sizes, int n_in,
                              void* d_out, int out_size, void* d_ws, size_t ws_size,
                              hipStream_t stream) {
    const float* input = (const float*)d_in[0];
    // d_in[1] = adj : UNUSED by the reference
    const float* W = (const float*)d_in[2];
    const float* a = (const float*)d_in[3];
    float* out = (float*)d_out;

    char* ws = (char*)d_ws;
    f16*   h16t   = (f16*)(ws);                                   // 128*16*1032*2 = 4,227,072 B
    f16*   u16    = (f16*)(ws + 4227072);                         // 524,288 B
    f16*   v16    = (f16*)(ws + 4227072 + 524288);                // 524,288 B
    float* s_src  = (float*)(ws + 4227072 + 2 * 524288);          // 524,288 B
    float* s_dst  = (float*)(ws + 4227072 + 3 * 524288);          // 524,288 B
    float* maxd_w = (float*)(ws + 4227072 + 4 * 524288);          // 512 B

    gat_proj<<<dim3(Bc * Hc * Nc / 256), dim3(256), 0, stream>>>(input, W, a, h16t,
                                                                 s_src, s_dst);
    gat_prep<<<dim3(Bc * Hc), dim3(256), 0, stream>>>(s_dst, u16, v16, maxd_w);
    gat_attn4<<<dim3(Bc * Hc, 2), dim3(512), 0, stream>>>(h16t, u16, v16, s_src,
                                                          maxd_w, out);
}

// Round 6
// 26.655 us; speedup vs baseline: 4.0373x; 1.0675x over previous
//
#include <hip/hip_runtime.h>

typedef _Float16 f16;
typedef f16 f16x8 __attribute__((ext_vector_type(8)));
typedef float f32x4 __attribute__((ext_vector_type(4)));

constexpr int Bc = 32, Nc = 1024, Dc = 64, Hc = 4, Ec = 16;
constexpr int HP = 1032;   // h_t pitch (f16): rows r,r+8 alias 2-way on b128 reads = free

// ---------------------------------------------------------------------------
// Kernel 1: h = input @ W per head. Stores h TRANSPOSED as f16 [bh][e][j]
// (MFMA B-operand layout) plus fp32 score vectors s_src/s_dst.
// ---------------------------------------------------------------------------
__global__ __launch_bounds__(256) void gat_proj(const float* __restrict__ input,
                                                const float* __restrict__ W,
                                                const float* __restrict__ a,
                                                f16* __restrict__ h16t,
                                                float* __restrict__ s_src,
                                                float* __restrict__ s_dst) {
    __shared__ float W_lds[Dc * Ec];
    __shared__ float a_lds[2 * Ec];

    const int tid = threadIdx.x;
    const int gid = blockIdx.x * 256 + tid;   // ((b*H + h)*N + n)
    const int n   = gid & (Nc - 1);
    const int bh  = gid >> 10;
    const int hh  = bh & (Hc - 1);
    const int b   = bh >> 2;

    ((float4*)W_lds)[tid] = ((const float4*)(W + hh * Dc * Ec))[tid];
    if (tid < 2 * Ec) a_lds[tid] = a[tid];
    __syncthreads();

    const float4* in_row = (const float4*)(input + ((size_t)b * Nc + n) * Dc);

    float acc[Ec];
#pragma unroll
    for (int e = 0; e < Ec; ++e) acc[e] = 0.f;

#pragma unroll
    for (int d4 = 0; d4 < Dc / 4; ++d4) {
        float4 x = in_row[d4];
        float xs[4] = {x.x, x.y, x.z, x.w};
#pragma unroll
        for (int k = 0; k < 4; ++k) {
            const float xv = xs[k];
            const float* wrow = &W_lds[(d4 * 4 + k) * Ec];
#pragma unroll
            for (int e = 0; e < Ec; ++e) acc[e] = fmaf(xv, wrow[e], acc[e]);
        }
    }

    // transposed f16 store: h16t[bh][e][n]  (lanes n-consecutive -> coalesced)
    f16* hb = h16t + (size_t)bh * Ec * HP + n;
#pragma unroll
    for (int e = 0; e < Ec; ++e) hb[e * HP] = (f16)acc[e];

    float sd = 0.f, ss = 0.f;
#pragma unroll
    for (int e = 0; e < Ec; ++e) {
        sd = fmaf(acc[e], a_lds[e], sd);        // a_dst = a[:E]
        ss = fmaf(acc[e], a_lds[Ec + e], ss);   // a_src = a[E:]
    }
    s_dst[gid] = sd;
    s_src[gid] = ss;
}

// ---------------------------------------------------------------------------
// Kernel 2: fused prep + attention.
//   P_ij = max(u_j, C_i*v_j) exactly (exp∘max = max∘exp, lrelu split),
//   u_j = exp(sd_j-maxd), v_j = exp(0.2(sd_j-maxd)),
//   C_i = min(1, exp(-0.8(s_i+maxd))).
//   out = (P @ h) * rcp(P @ 1) via mfma_f32_16x16x32_f16.
// Block = (bh, i-half): 512 thr, 8 waves x 4 i-tiles x K=1024. u,v,h in LDS.
// ---------------------------------------------------------------------------
__global__ __launch_bounds__(512) void gat_attn5(const f16* __restrict__ h16t,
                                                 const float* __restrict__ s_src,
                                                 const float* __restrict__ s_dst,
                                                 float* __restrict__ out) {
    __shared__ alignas(16) f16 h_t[Ec * HP];     // 33 KB
    __shared__ alignas(16) f16 u_lds[Nc];        // 2 KB
    __shared__ alignas(16) f16 v_lds[Nc];        // 2 KB
    __shared__ float red[8];

    const int bh    = blockIdx.x;      // 0..127
    const int ihalf = blockIdx.y;      // 0..1
    const int tid   = threadIdx.x;
    const int lane  = tid & 63;
    const int wave  = tid >> 6;        // 0..7
    const int row   = lane & 15;       // A-row / D-col index
    const int quad  = lane >> 4;       // K-quadrant

    // ---- stage h_t (2064 float4 chunks) ----
    {
        const float4* src = (const float4*)(h16t + (size_t)bh * Ec * HP);
        float4* dst = (float4*)h_t;
        dst[tid]        = src[tid];
        dst[512 + tid]  = src[512 + tid];
        dst[1024 + tid] = src[1024 + tid];
        dst[1536 + tid] = src[1536 + tid];
        if (tid < 16) dst[2048 + tid] = src[2048 + tid];
    }

    // ---- block max of s_dst (identical in both blocks of this bh) ----
    const float sd0 = s_dst[bh * Nc + tid];
    const float sd1 = s_dst[bh * Nc + 512 + tid];
    {
        float m = fmaxf(sd0, sd1);
#pragma unroll
        for (int off = 1; off < 64; off <<= 1) m = fmaxf(m, __shfl_xor(m, off, 64));
        if (lane == 0) red[wave] = m;
    }
    __syncthreads();
    float maxd = red[0];
#pragma unroll
    for (int w = 1; w < 8; ++w) maxd = fmaxf(maxd, red[w]);

    // ---- u, v into LDS ----
    u_lds[tid]       = (f16)__expf(sd0 - maxd);
    u_lds[512 + tid] = (f16)__expf(sd1 - maxd);
    v_lds[tid]       = (f16)__expf(0.2f * (sd0 - maxd));
    v_lds[512 + tid] = (f16)__expf(0.2f * (sd1 - maxd));

    // ---- per-row C_i (hide latency before the barrier) ----
    const int ibase = ihalf * 512 + wave * 64;
    f16x8 C8[4];
#pragma unroll
    for (int it = 0; it < 4; ++it) {
        const float si = s_src[bh * Nc + ibase + it * 16 + row];
        const float c1 = si + maxd;
        const float Cf = (c1 >= 0.f) ? __expf(-0.8f * c1) : 1.0f;
        const f16 ch = (f16)Cf;
        C8[it] = (f16x8){ch, ch, ch, ch, ch, ch, ch, ch};
    }
    __syncthreads();

    f32x4 accN[4] = {};
    f32x4 accD[4] = {};
    const f16 o1 = (f16)1.f;
    const f16x8 ones = {o1, o1, o1, o1, o1, o1, o1, o1};

    const f16* up = u_lds + quad * 8;
    const f16* vp = v_lds + quad * 8;
    const f16* bp = h_t + row * HP + quad * 8;

#pragma unroll 4
    for (int kt = 0; kt < 32; ++kt) {
        const f16x8 u8 = *(const f16x8*)(up + kt * 32);
        const f16x8 v8 = *(const f16x8*)(vp + kt * 32);
        const f16x8 b8 = *(const f16x8*)(bp + kt * 32);
#pragma unroll
        for (int it = 0; it < 4; ++it) {
            const f16x8 p = __builtin_elementwise_max(u8, C8[it] * v8);
            accN[it] = __builtin_amdgcn_mfma_f32_16x16x32_f16(p, b8,   accN[it], 0, 0, 0);
            accD[it] = __builtin_amdgcn_mfma_f32_16x16x32_f16(p, ones, accD[it], 0, 0, 0);
        }
    }

    // ---- epilogue: D row = quad*4 + r, col = row (m89 C/D layout) ----
#pragma unroll
    for (int it = 0; it < 4; ++it) {
#pragma unroll
        for (int r = 0; r < 4; ++r) {
            const float inv = __builtin_amdgcn_rcpf(accD[it][r]);
            const int i = ibase + it * 16 + quad * 4 + r;
            out[((size_t)(bh * Nc + i)) * Ec + row] = accN[it][r] * inv;
        }
    }
}

extern "C" void kernel_launch(void* const* d_in, const int* in_sizes, int n_in,
                              void* d_out, int out_size, void* d_ws, size_t ws_size,
                              hipStream_t stream) {
    const float* input = (const float*)d_in[0];
    // d_in[1] = adj : UNUSED by the reference
    const float* W = (const float*)d_in[2];
    const float* a = (const float*)d_in[3];
    float* out = (float*)d_out;

    char* ws = (char*)d_ws;
    f16*   h16t  = (f16*)(ws);                       // 128*16*1032*2 = 4,227,072 B
    float* s_src = (float*)(ws + 4227072);           // 524,288 B
    float* s_dst = (float*)(ws + 4227072 + 524288);  // 524,288 B

    gat_proj<<<dim3(Bc * Hc * Nc / 256), dim3(256), 0, stream>>>(input, W, a, h16t,
                                                                 s_src, s_dst);
    gat_attn5<<<dim3(Bc * Hc, 2), dim3(512), 0, stream>>>(h16t, s_src, s_dst, out);
}